// Round 6
// baseline (149.055 us; speedup 1.0000x reference)
//
#include <hip/hip_runtime.h>
#include <math.h>

// ---------------- problem constants ----------------
#define NB 8          // batch
#define NM 16         // modes
#define NPH 8         // photons
#define NSTATES 12870 // C(16,8)
#define NSUB 256      // 2^NPH column subsets
#define OUTS 128
#define NTILES 824    // sum over classes of ceil(R/4)*ceil(C/4)
#define NSLOTS (NTILES*16) // 13184
#define NSG 16        // s-groups of 16 (partial-accumulation granularity)
#define SPH 16        // s per k_fused block
#define NTG 4         // tile groups
#define TILES_PER_TG 206
#define SLOTS_PER_PG 64
#define NPGBLK 206    // 206*64 == NSLOTS

// ---------------- compile-time tables ----------------
struct Tables {
  int binom[17][9];
  unsigned char cls_masks[256]; // 8-bit masks sorted by (popcount, value)
  int cls_off[10];              // offsets into cls_masks per popcount
  int nt1[9], nt2[9];           // 4-tiles per dim per class
  int tile_off[10];
};

constexpr int cpopc(int x){ int c=0; while(x){ c += x & 1; x >>= 1; } return c; }

constexpr Tables make_tables(){
  Tables t{};
  for (int n=0;n<=16;n++)
    for (int k=0;k<=8;k++){
      if (k==0) t.binom[n][k]=1;
      else if (n==0) t.binom[n][k]=0;
      else t.binom[n][k]=t.binom[n-1][k-1]+t.binom[n-1][k];
    }
  int idx=0;
  for (int p=0;p<=8;p++){
    t.cls_off[p]=idx;
    for (int m=0;m<256;m++) if (cpopc(m)==p) t.cls_masks[idx++]=(unsigned char)m;
  }
  t.cls_off[9]=idx; // 256
  int toff=0;
  for (int c=0;c<=8;c++){
    int R=t.binom[8][c], C=t.binom[8][8-c];
    t.nt1[c]=(R+3)/4; t.nt2[c]=(C+3)/4;
    t.tile_off[c]=toff; toff += t.nt1[c]*t.nt2[c];
  }
  t.tile_off[9]=toff;
  return t;
}

constexpr Tables HTBL = make_tables();
static_assert(HTBL.tile_off[9]==NTILES, "tile count");
static_assert(HTBL.cls_off[9]==256, "mask count");
__device__ const Tables TBL = HTBL;

// ---------------- workspace layout (bytes) ----------------
#define WS_CNT    0                 // 4 B ticket (zeroed by k_fused blk 0)
#define WS_GACC   256               // [NB][OUTS] float = 4096 (zeroed by k_fused blk 0)
#define WS_GNORM  4608              // [NB] float = 32 (zeroed by k_fused blk 0)
#define WS_TMAP   8192              // NSLOTS ints = 52736 (pads never read)
#define WS_PART   65536             // [NB][NSG][NSLOTS] float2 = 13500416

// ---------------- complex helpers ----------------
__device__ __forceinline__ float2 cmul(float2 a, float2 b){
  return make_float2(fmaf(a.x,b.x,-(a.y*b.y)), fmaf(a.x,b.y, a.y*b.x));
}
__device__ __forceinline__ void cmac(float2& acc, float2 a, float2 b){
  acc.x = fmaf(a.x, b.x, acc.x); acc.x = fmaf(-a.y, b.y, acc.x);
  acc.y = fmaf(a.x, b.y, acc.y); acc.y = fmaf(a.y, b.x, acc.y);
}

// ---------------- K_A: fused setup + barrier-light Ryser main ----------
// grid 512 = NB(8) x NSG(16) x NTG(4); 64 KB LDS, 256 thr -> 2 blocks/CU.
// Prologue (unitaries, Uin) runs redundantly per block in LDS scratch aliased
// over the P table; each thread then extracts its 8 V values into REGISTERS
// (bit-identical summation order to the old k_setup), the fill builds all 256
// subset products per (table,s) via a fully unrolled register DP, one barrier,
// then the 4x4 register-tiled combine. tg==3 blocks also write the tile map.
// Block 0 zeroes the K_B accumulators.
__global__ __launch_bounds__(256) void k_fused(
    const float* __restrict__ x, const float* __restrict__ th1,
    const float* __restrict__ th2, const float* __restrict__ mr,
    const float* __restrict__ mi, const int* __restrict__ rows, char* ws)
{
  __shared__ float2 P[32][256];      // 64 KB; row ts = table*16+s, col swizzled
  float2* __restrict__ part = (float2*)(ws + WS_PART);
  int tid = threadIdx.x;
  int blk = blockIdx.x;
  int b = blk >> 6, rest = blk & 63, sg = rest >> 2, tg = rest & 3;
  int sbase = sg * SPH;

  if (blk == 0){
    float* g = (float*)(ws + WS_GACC);
    for (int i = tid; i < NB*OUTS; i += 256) g[i] = 0.0f;
    if (tid < NB) ((float*)(ws + WS_GNORM))[tid] = 0.0f;
    if (tid == 0) *(int*)(ws + WS_CNT) = 0;
  }

  // ---- prologue scratch aliased over P (dead before fill) ----
  float2 (*T1)[NM]  = reinterpret_cast<float2(*)[NM]>(P[0]);
  float2 (*T2)[NM]  = reinterpret_cast<float2(*)[NM]>(P[1]);
  float2 (*Am)[NM]  = reinterpret_cast<float2(*)[NM]>(P[2]);
  float2 (*Bm)[NM]  = reinterpret_cast<float2(*)[NM]>(P[3]);
  float2 (*EA)[NPH] = reinterpret_cast<float2(*)[NPH]>(P[4]);   // P[4][0..127]
  float2* exP = P[4] + 128;                                      // P[4][128..143]
  float2 (*UinL)[NPH] = reinterpret_cast<float2(*)[NPH]>(P[5]); // P[5][0..127]

  {
    int r = tid >> 4, cc = tid & 15;
    float sn, cs;
    sincosf(th1[r], &sn, &cs);
    float a = mr[0*256 + tid], bb = mi[0*256 + tid];   // M0[r][cc]
    T1[r][cc] = make_float2(cs*a - sn*bb, cs*bb + sn*a);
    sincosf(th2[r], &sn, &cs);
    float a2 = mr[2*256 + tid], b2 = mi[2*256 + tid];  // M2[r][cc]
    T2[r][cc] = make_float2(cs*a2 - sn*b2, cs*b2 + sn*a2);
    if (tid < NM){ float s2, c2; sincosf(x[b*NM + tid], &s2, &c2); exP[tid] = make_float2(c2, s2); }
  }
  __syncthreads();
  {
    int r = tid >> 4, cc = tid & 15;
    float2 accA = make_float2(0,0), accB = make_float2(0,0);
    for (int m=0;m<NM;m++){
      float2 m1 = make_float2(mr[1*256 + r*16+m], mi[1*256 + r*16+m]);
      cmac(accA, m1, T1[m][cc]);
      float2 m3 = make_float2(mr[3*256 + r*16+m], mi[3*256 + r*16+m]);
      cmac(accB, m3, T2[m][cc]);
    }
    Am[r][cc] = accA; Bm[r][cc] = accB;   // rows 2,3: disjoint from rows 0,1
  }
  __syncthreads();
  if (tid < NM*NPH){ int m = tid >> 3, n = tid & 7; EA[m][n] = cmul(exP[m], Am[m][n]); }
  __syncthreads();
  if (tid < NM*NPH){
    int p = tid >> 3, n = tid & 7;
    float2 acc = make_float2(0,0);
    for (int m=0;m<NM;m++) cmac(acc, Bm[p][m], EA[m][n]);
    UinL[p][n] = acc;
  }
  __syncthreads();

  // ---- per-thread V extraction into registers (same sum order as k_setup) --
  int ts = tid >> 3;                 // 0..31
  int table = ts >> 4, sl = ts & 15;
  int sv = sbase + sl;
  float2 v[8];
  {
    #pragma unroll
    for (int j=0;j<8;j++){
      float2 a = make_float2(0,0);
      int m = table*8 + j;
      #pragma unroll
      for (int jj=0;jj<NPH;jj++)
        if ((sv>>jj) & 1){ a.x += UinL[m][jj].x; a.y += UinL[m][jj].y; }
      v[j] = a;
    }
  }
  __syncthreads();   // all UinL reads done; prologue scratch dead

  // ---- fill: thread -> (ts, chunk of 32 t-values), register DP ----
  {
    int chunk = tid & 7;
    int t0 = chunk << 5;
    // high bits (t bits 5..7), order v7,v6,v5 = old chain order
    float2 ph = make_float2((table==0 && (__popc(sv)&1)) ? -1.0f : 1.0f, 0.0f);
    if (chunk & 4) ph = cmul(ph, v[7]);
    if (chunk & 2) ph = cmul(ph, v[6]);
    if (chunk & 1) ph = cmul(ph, v[5]);
    float2 p[32];
    p[0] = ph;
    #pragma unroll
    for (int u=1; u<32; u++){
      int par = u & (u-1);
      int lb = (u&1) ? 0 : ((u&2) ? 1 : ((u&4) ? 2 : ((u&8) ? 3 : 4)));
      p[u] = cmul(p[par], v[lb]);
    }
    int swz = (ts & 15) << 1;        // XOR on t bits 1..4 (bit0 preserved)
    #pragma unroll
    for (int u=0; u<32; u+=2){
      int tc = (t0 + u) ^ swz;
      *(float4*)&P[ts][tc] = make_float4(p[u].x, p[u].y, p[u+1].x, p[u+1].y);
    }
  }

  // combine-thread tile masks (registers + const tables only)
  bool active = tid < TILES_PER_TG;
  int tile = tg + 4*tid;
  int t1v[4] = {0,0,0,0}, t2v[4] = {0,0,0,0};
  if (active){
    int c = 0;
    while (tile >= TBL.tile_off[c+1]) c++;
    int local = tile - TBL.tile_off[c];
    int n2 = TBL.nt2[c];
    int ti = local / n2, tj = local - ti*n2;
    int R = TBL.binom[8][c], C2 = TBL.binom[8][8-c];
    #pragma unroll
    for (int i=0;i<4;i++){ int r1 = ti*4+i; t1v[i] = (r1<R) ? (int)TBL.cls_masks[TBL.cls_off[c]+r1] : 0; }
    #pragma unroll
    for (int j=0;j<4;j++){ int r2 = tj*4+j; t2v[j] = (r2<C2) ? (int)TBL.cls_masks[TBL.cls_off[8-c]+r2] : 0; }
  }
  __syncthreads();   // P table ready

  // ---- 4x4 register-tiled combine over this block's 16 s ----
  if (active){
    float2 acc[4][4] = {};
    for (int s=0;s<SPH;s++){
      int swz = s << 1;
      float2 av[4], bv[4];
      #pragma unroll
      for (int i=0;i<4;i++) av[i] = P[s][t1v[i] ^ swz];
      #pragma unroll
      for (int j=0;j<4;j++) bv[j] = P[16+s][t2v[j] ^ swz];
      #pragma unroll
      for (int i=0;i<4;i++)
        #pragma unroll
        for (int j=0;j<4;j++) cmac(acc[i][j], av[i], bv[j]);
    }
    float2* dst = part + (size_t)(b*NSG + sg)*NSLOTS + (size_t)tile*16;
    #pragma unroll
    for (int i=0;i<4;i++)
      #pragma unroll
      for (int j=0;j<4;j++) dst[i*4+j] = acc[i][j];
  }

  // ---- tile map: tg==3 blocks rank 101 states each ----
  if (tg == 3){
    int idx = blk >> 2;              // 0..127
    int kb = idx * 101;
    int ke = min(NSTATES, kb + 101);
    int k = kb + tid;
    if (k < ke){
      int t1=0, t2=0;
      #pragma unroll
      for (int i=0;i<NPH;i++){
        int rr = rows[k*NPH+i];
        if (rr < 8) t1 |= 1 << rr; else t2 |= 1 << (rr-8);
      }
      int c1 = __popc(t1);
      int rk1=0, cnt=0;
      #pragma unroll
      for (int bb=0;bb<8;bb++) if ((t1>>bb)&1){ cnt++; rk1 += TBL.binom[bb][cnt]; }
      int rk2=0; cnt=0;
      #pragma unroll
      for (int bb=0;bb<8;bb++) if ((t2>>bb)&1){ cnt++; rk2 += TBL.binom[bb][cnt]; }
      int tl = TBL.tile_off[c1] + (rk1>>2)*TBL.nt2[c1] + (rk2>>2);
      int slot = ((rk1&3)<<2) | (rk2&3);
      ((int*)(ws + WS_TMAP))[tl*16 + slot] = k;
    }
  }
}

// ---------------- K_B: slot-driven reduce + gemm + last-block final -------
// grid NPGBLK(206) x 512 threads. Block owns 64 consecutive slots.
// (A) analytic pad + tmap -> krow; (B) coalesced part reduce -> prob LDS;
// (C) per-b norm partial -> atomicAdd gnorm; (D) gemm quarters -> hacc;
// (E) atomicAdd quarter-sums into gacc; (F) ticket: last block divides,
// adds bias, writes out (fence/ticket pattern verified in round 1).
__global__ __launch_bounds__(512) void k_tail(
    const float* __restrict__ wgt, const float* __restrict__ bias,
    char* ws, float* __restrict__ out)
{
  __shared__ float prob[NB][SLOTS_PER_PG];   // 2 KB
  __shared__ int   krow[SLOTS_PER_PG];       // 256 B
  __shared__ float hacc[4][NB][OUTS];        // 16 KB
  __shared__ int lastflag;
  int tid = threadIdx.x;
  int blk = blockIdx.x;
  int slot0 = blk * SLOTS_PER_PG;

  if (tid < SLOTS_PER_PG){
    int slot = slot0 + tid;
    int tile = slot >> 4;
    int c = 0;
    while (tile >= TBL.tile_off[c+1]) c++;
    int local = tile - TBL.tile_off[c];
    int n2 = TBL.nt2[c];
    int ti = local / n2, tj = local - ti*n2;
    int r1 = ti*4 + ((tid >> 2) & 3);
    int r2 = tj*4 + (tid & 3);
    bool pad = (r1 >= TBL.binom[8][c]) || (r2 >= TBL.binom[8][8-c]);
    krow[tid] = pad ? -1 : ((const int*)(ws + WS_TMAP))[slot];
  }
  __syncthreads();

  // (B) coalesced partial reduce: one (b, sl) per thread
  const float2* __restrict__ part = (const float2*)(ws + WS_PART);
  {
    int b = tid >> 6, sl = tid & 63;
    float2 amp = make_float2(0,0);
    #pragma unroll
    for (int g=0; g<NSG; g++){
      float2 v = part[(size_t)(b*NSG + g)*NSLOTS + slot0 + sl];
      amp.x += v.x; amp.y += v.y;
    }
    prob[b][sl] = (krow[sl] >= 0) ? fmaf(amp.x, amp.x, amp.y*amp.y) : 0.0f;
  }
  __syncthreads();

  // (C) per-b norm partial: one wave per b, lane 0 atomics
  {
    int b = tid >> 6, l = tid & 63;
    float v = prob[b][l];
    #pragma unroll
    for (int off=32; off>0; off>>=1) v += __shfl_down(v, off);
    if (l == 0) atomicAdd((float*)(ws + WS_GNORM) + b, v);
  }

  // (D) gemm: quarter q owns 16 slots, thread owns column o
  {
    int q = tid >> 7, o = tid & 127;
    float acc[NB] = {0,0,0,0,0,0,0,0};
    int sbeg = q*16, send = sbeg + 16;
    #pragma unroll 4
    for (int sl = sbeg; sl < send; sl++){
      int kr = krow[sl]; if (kr < 0) kr = 0;   // prob already 0 for pads
      float wv = wgt[(size_t)kr * OUTS + o];
      #pragma unroll
      for (int b=0;b<NB;b++) acc[b] = fmaf(prob[b][sl], wv, acc[b]);
    }
    #pragma unroll
    for (int b=0;b<NB;b++) hacc[q][b][o] = acc[b];
  }
  __syncthreads();

  // (E) quarter-sum -> global atomic accumulate
  float* gacc = (float*)(ws + WS_GACC);
  for (int idx = tid; idx < NB*OUTS; idx += 512){
    float s = hacc[0][0][idx] + hacc[1][0][idx] + hacc[2][0][idx] + hacc[3][0][idx];
    atomicAdd(gacc + idx, s);
  }

  // (F) last-block finalization (threadfence-reduction pattern)
  __threadfence();
  __syncthreads();
  if (tid == 0) lastflag = (atomicAdd((int*)(ws + WS_CNT), 1) == NPGBLK-1) ? 1 : 0;
  __syncthreads();
  if (lastflag){
    __threadfence();
    const float* gnorm = (const float*)(ws + WS_GNORM);
    for (int idx = tid; idx < NB*OUTS; idx += 512){
      int b = idx >> 7, o = idx & 127;
      out[idx] = gacc[idx] / gnorm[b] + bias[o];
    }
  }
}

// ---------------- launch ----------------
extern "C" void kernel_launch(void* const* d_in, const int* in_sizes, int n_in,
                              void* d_out, int out_size, void* d_ws, size_t ws_size,
                              hipStream_t stream) {
  const float* x    = (const float*)d_in[0];
  const float* th1  = (const float*)d_in[1];
  const float* th2  = (const float*)d_in[2];
  const float* mr   = (const float*)d_in[3];
  const float* mi   = (const float*)d_in[4];
  const float* wgt  = (const float*)d_in[5];
  const float* bias = (const float*)d_in[6];
  const int*   rows = (const int*)d_in[7];
  float* out = (float*)d_out;
  char* ws = (char*)d_ws;

  k_fused<<<NB*NSG*NTG, 256, 0, stream>>>(x, th1, th2, mr, mi, rows, ws);
  k_tail<<<NPGBLK, 512, 0, stream>>>(wgt, bias, ws, out);
}

// Round 8
// 120.980 us; speedup vs baseline: 1.2321x; 1.2321x over previous
//
#include <hip/hip_runtime.h>
#include <math.h>

// ---------------- problem constants ----------------
#define NB 8          // batch
#define NM 16         // modes
#define NPH 8         // photons
#define NSTATES 12870 // C(16,8)
#define NSUB 256      // 2^NPH column subsets
#define OUTS 128
#define NTILES 824    // sum over classes of ceil(R/4)*ceil(C/4)
#define NSLOTS (NTILES*16) // 13184
#define NSG 16        // s-groups of 16
#define SPH 16        // s per producer block
#define NTG 4         // tile groups
#define TILES_PER_TG 206
#define NGRID 512     // NB * NSG * NTG
#define SLOTS_P2 32
#define NP2 412       // 412*32 == NSLOTS

// ---------------- compile-time tables ----------------
struct Tables {
  int binom[17][9];
  unsigned char cls_masks[256];
  int cls_off[10];
  int nt1[9], nt2[9];
  int tile_off[10];
};

constexpr int cpopc(int x){ int c=0; while(x){ c += x & 1; x >>= 1; } return c; }

constexpr Tables make_tables(){
  Tables t{};
  for (int n=0;n<=16;n++)
    for (int k=0;k<=8;k++){
      if (k==0) t.binom[n][k]=1;
      else if (n==0) t.binom[n][k]=0;
      else t.binom[n][k]=t.binom[n-1][k-1]+t.binom[n-1][k];
    }
  int idx=0;
  for (int p=0;p<=8;p++){
    t.cls_off[p]=idx;
    for (int m=0;m<256;m++) if (cpopc(m)==p) t.cls_masks[idx++]=(unsigned char)m;
  }
  t.cls_off[9]=idx; // 256
  int toff=0;
  for (int c=0;c<=8;c++){
    int R=t.binom[8][c], C=t.binom[8][8-c];
    t.nt1[c]=(R+3)/4; t.nt2[c]=(C+3)/4;
    t.tile_off[c]=toff; toff += t.nt1[c]*t.nt2[c];
  }
  t.tile_off[9]=toff;
  return t;
}

constexpr Tables HTBL = make_tables();
static_assert(HTBL.tile_off[9]==NTILES, "tile count");
static_assert(HTBL.cls_off[9]==256, "mask count");
__device__ const Tables TBL = HTBL;

// ---------------- workspace layout (bytes) ----------------
#define WS_TMAP   0                 // NSLOTS ints = 52736 (pads never read)
#define WS_BSUM2  53248             // [NP2][NB] float = 13184 -> 66432
#define WS_POUT2  66560             // [NP2][NB*OUTS] float = 1687552 -> 1754112
#define WS_PART   1754112           // [NB][NSG][NSLOTS] float2 = 13500416

// ---------------- complex helpers ----------------
__device__ __forceinline__ float2 cmul(float2 a, float2 b){
  return make_float2(fmaf(a.x,b.x,-(a.y*b.y)), fmaf(a.x,b.y, a.y*b.x));
}
__device__ __forceinline__ void cmac(float2& acc, float2 a, float2 b){
  acc.x = fmaf(a.x, b.x, acc.x); acc.x = fmaf(-a.y, b.y, acc.x);
  acc.y = fmaf(a.x, b.y, acc.y); acc.y = fmaf(a.y, b.x, acc.y);
}

// ============ K1: fused setup + barrier-light Ryser main (R6-verified) =====
// grid 512 = NB(8) x NSG(16) x NTG(4); 64 KB LDS, 256 thr -> 2 blocks/CU.
__global__ __launch_bounds__(256) void k_p1(
    const float* __restrict__ x, const float* __restrict__ th1,
    const float* __restrict__ th2, const float* __restrict__ mr,
    const float* __restrict__ mi, const int* __restrict__ rows, char* ws)
{
  __shared__ float2 P[32][256];      // 64 KB; row ts = table*16+s, col swizzled
  float2* __restrict__ part = (float2*)(ws + WS_PART);
  int tid = threadIdx.x;
  int blk = blockIdx.x;
  int b = blk >> 6, rest = blk & 63, sg = rest >> 2, tg = rest & 3;
  int sbase = sg * SPH;

  // prologue scratch aliased over P (dead before fill)
  float2 (*T1)[NM]  = reinterpret_cast<float2(*)[NM]>(P[0]);
  float2 (*T2)[NM]  = reinterpret_cast<float2(*)[NM]>(P[1]);
  float2 (*Am)[NM]  = reinterpret_cast<float2(*)[NM]>(P[2]);
  float2 (*Bm)[NM]  = reinterpret_cast<float2(*)[NM]>(P[3]);
  float2 (*EA)[NPH] = reinterpret_cast<float2(*)[NPH]>(P[4]);
  float2* exP = P[4] + 128;
  float2 (*UinL)[NPH] = reinterpret_cast<float2(*)[NPH]>(P[5]);

  {
    int r = tid >> 4, cc = tid & 15;
    float sn, cs;
    sincosf(th1[r], &sn, &cs);
    float a = mr[0*256 + tid], bb = mi[0*256 + tid];
    T1[r][cc] = make_float2(cs*a - sn*bb, cs*bb + sn*a);
    sincosf(th2[r], &sn, &cs);
    float a2 = mr[2*256 + tid], b2 = mi[2*256 + tid];
    T2[r][cc] = make_float2(cs*a2 - sn*b2, cs*b2 + sn*a2);
    if (tid < NM){ float s2, c2; sincosf(x[b*NM + tid], &s2, &c2); exP[tid] = make_float2(c2, s2); }
  }
  __syncthreads();
  {
    int r = tid >> 4, cc = tid & 15;
    float2 accA = make_float2(0,0), accB = make_float2(0,0);
    for (int m=0;m<NM;m++){
      float2 m1 = make_float2(mr[1*256 + r*16+m], mi[1*256 + r*16+m]);
      cmac(accA, m1, T1[m][cc]);
      float2 m3 = make_float2(mr[3*256 + r*16+m], mi[3*256 + r*16+m]);
      cmac(accB, m3, T2[m][cc]);
    }
    Am[r][cc] = accA; Bm[r][cc] = accB;
  }
  __syncthreads();
  if (tid < NM*NPH){ int m = tid >> 3, n = tid & 7; EA[m][n] = cmul(exP[m], Am[m][n]); }
  __syncthreads();
  if (tid < NM*NPH){
    int p = tid >> 3, n = tid & 7;
    float2 acc = make_float2(0,0);
    for (int m=0;m<NM;m++) cmac(acc, Bm[p][m], EA[m][n]);
    UinL[p][n] = acc;
  }
  __syncthreads();

  // per-thread V extraction into registers (same sum order as original)
  int ts = tid >> 3;
  int table = ts >> 4, sl = ts & 15;
  int sv = sbase + sl;
  float2 v[8];
  {
    #pragma unroll
    for (int j=0;j<8;j++){
      float2 a = make_float2(0,0);
      int m = table*8 + j;
      #pragma unroll
      for (int jj=0;jj<NPH;jj++)
        if ((sv>>jj) & 1){ a.x += UinL[m][jj].x; a.y += UinL[m][jj].y; }
      v[j] = a;
    }
  }
  __syncthreads();   // prologue scratch dead

  // fill: register DP (bit-identical order), swizzled LDS write
  {
    int chunk = tid & 7;
    int t0 = chunk << 5;
    float2 ph = make_float2((table==0 && (__popc(sv)&1)) ? -1.0f : 1.0f, 0.0f);
    if (chunk & 4) ph = cmul(ph, v[7]);
    if (chunk & 2) ph = cmul(ph, v[6]);
    if (chunk & 1) ph = cmul(ph, v[5]);
    float2 p[32];
    p[0] = ph;
    #pragma unroll
    for (int u=1; u<32; u++){
      int par = u & (u-1);
      int lb = (u&1) ? 0 : ((u&2) ? 1 : ((u&4) ? 2 : ((u&8) ? 3 : 4)));
      p[u] = cmul(p[par], v[lb]);
    }
    int swz = (ts & 15) << 1;
    #pragma unroll
    for (int u=0; u<32; u+=2){
      int tc = (t0 + u) ^ swz;
      *(float4*)&P[ts][tc] = make_float4(p[u].x, p[u].y, p[u+1].x, p[u+1].y);
    }
  }

  // combine-thread tile masks
  bool active = tid < TILES_PER_TG;
  int tile = tg + 4*tid;
  int t1v[4] = {0,0,0,0}, t2v[4] = {0,0,0,0};
  if (active){
    int c = 0;
    while (tile >= TBL.tile_off[c+1]) c++;
    int local = tile - TBL.tile_off[c];
    int n2 = TBL.nt2[c];
    int ti = local / n2, tj = local - ti*n2;
    int R = TBL.binom[8][c], C2 = TBL.binom[8][8-c];
    #pragma unroll
    for (int i=0;i<4;i++){ int r1 = ti*4+i; t1v[i] = (r1<R) ? (int)TBL.cls_masks[TBL.cls_off[c]+r1] : 0; }
    #pragma unroll
    for (int j=0;j<4;j++){ int r2 = tj*4+j; t2v[j] = (r2<C2) ? (int)TBL.cls_masks[TBL.cls_off[8-c]+r2] : 0; }
  }
  __syncthreads();   // P table ready

  if (active){
    float2 acc[4][4] = {};
    for (int s=0;s<SPH;s++){
      int swz = s << 1;
      float2 av[4], bv[4];
      #pragma unroll
      for (int i=0;i<4;i++) av[i] = P[s][t1v[i] ^ swz];
      #pragma unroll
      for (int j=0;j<4;j++) bv[j] = P[16+s][t2v[j] ^ swz];
      #pragma unroll
      for (int i=0;i<4;i++)
        #pragma unroll
        for (int j=0;j<4;j++) cmac(acc[i][j], av[i], bv[j]);
    }
    float2* dst = part + (size_t)(b*NSG + sg)*NSLOTS + (size_t)tile*16;
    #pragma unroll
    for (int i=0;i<4;i++)
      #pragma unroll
      for (int j=0;j<4;j++) dst[i*4+j] = acc[i][j];
  }

  // tile map: tg==3 blocks rank 101 states each
  if (tg == 3){
    int idx = blk >> 2;
    int kb = idx * 101;
    int ke = min(NSTATES, kb + 101);
    int k = kb + tid;
    if (k < ke){
      int t1=0, t2=0;
      #pragma unroll
      for (int i=0;i<NPH;i++){
        int rr = rows[k*NPH+i];
        if (rr < 8) t1 |= 1 << rr; else t2 |= 1 << (rr-8);
      }
      int c1 = __popc(t1);
      int rk1=0, cnt=0;
      #pragma unroll
      for (int bb=0;bb<8;bb++) if ((t1>>bb)&1){ cnt++; rk1 += TBL.binom[bb][cnt]; }
      int rk2=0; cnt=0;
      #pragma unroll
      for (int bb=0;bb<8;bb++) if ((t2>>bb)&1){ cnt++; rk2 += TBL.binom[bb][cnt]; }
      int tl = TBL.tile_off[c1] + (rk1>>2)*TBL.nt2[c1] + (rk2>>2);
      int slot = ((rk1&3)<<2) | (rk2&3);
      ((int*)(ws + WS_TMAP))[tl*16 + slot] = k;
    }
  }
}

// ============ K2: slot-driven reduce + gemm partials (non-atomic) ==========
// grid NP2(412) x 256. Block owns 32 consecutive slots.
__global__ __launch_bounds__(256) void k_p2(const float* __restrict__ wgt, char* ws)
{
  __shared__ float prob[NB*SLOTS_P2];   // 256 floats
  __shared__ int   krow[SLOTS_P2];
  __shared__ float hacc[2*NB*OUTS];     // 2048 floats (8 KB)
  int tid = threadIdx.x;
  int blk = blockIdx.x;
  int slot0 = blk * SLOTS_P2;

  if (tid < SLOTS_P2){
    int slot = slot0 + tid;
    int tile = slot >> 4;
    int c = 0;
    while (tile >= TBL.tile_off[c+1]) c++;
    int local = tile - TBL.tile_off[c];
    int n2 = TBL.nt2[c];
    int ti = local / n2, tj = local - ti*n2;
    int r1 = ti*4 + ((slot >> 2) & 3);
    int r2 = tj*4 + (slot & 3);
    bool pad = (r1 >= TBL.binom[8][c]) || (r2 >= TBL.binom[8][8-c]);
    krow[tid] = pad ? -1 : ((const int*)(ws + WS_TMAP))[slot];
  }
  __syncthreads();

  // coalesced partial reduce: one (b, sl) per thread + norm partial
  const float2* __restrict__ part = (const float2*)(ws + WS_PART);
  float* __restrict__ bsum2 = (float*)(ws + WS_BSUM2);
  {
    int b = tid >> 5, sl = tid & 31;
    float2 amp = make_float2(0,0);
    #pragma unroll
    for (int g=0; g<NSG; g++){
      float2 v = part[(size_t)(b*NSG + g)*NSLOTS + slot0 + sl];
      amp.x += v.x; amp.y += v.y;
    }
    float pr = (krow[sl] >= 0) ? fmaf(amp.x, amp.x, amp.y*amp.y) : 0.0f;
    prob[b*SLOTS_P2 + sl] = pr;
    float v = pr;
    #pragma unroll
    for (int off=16; off>0; off>>=1) v += __shfl_down(v, off, 32);
    if (sl == 0) bsum2[blk*NB + b] = v;
  }
  __syncthreads();

  // gemm: half h owns 16 slots, thread owns column o
  {
    int h = tid >> 7, o = tid & 127;
    float acc[NB] = {0,0,0,0,0,0,0,0};
    int sbeg = h*16, send = sbeg + 16;
    #pragma unroll 4
    for (int sl = sbeg; sl < send; sl++){
      int kr = krow[sl]; if (kr < 0) kr = 0;   // prob already 0 for pads
      float wv = wgt[(size_t)kr * OUTS + o];
      #pragma unroll
      for (int b=0;b<NB;b++) acc[b] = fmaf(prob[b*SLOTS_P2 + sl], wv, acc[b]);
    }
    #pragma unroll
    for (int b=0;b<NB;b++) hacc[h*(NB*OUTS) + b*OUTS + o] = acc[b];
  }
  __syncthreads();

  float* __restrict__ pout2 = (float*)(ws + WS_POUT2);
  for (int idx = tid; idx < NB*OUTS; idx += 256)
    pout2[(size_t)blk*(NB*OUTS) + idx] = hacc[idx] + hacc[NB*OUTS + idx];
}

// ============ K3: final reduce ==========
// grid NB x 256. out = (sum_s pout2)/(sum bsum2) + bias
__global__ __launch_bounds__(256) void k_p3(
    const float* __restrict__ bias, const char* __restrict__ ws,
    float* __restrict__ out)
{
  __shared__ float accs[2*OUTS];
  __shared__ float wred[4];
  int tid = threadIdx.x, b = blockIdx.x;
  const float* __restrict__ bsum2 = (const float*)(ws + WS_BSUM2);
  const float* __restrict__ pout2 = (const float*)(ws + WS_POUT2);

  float v = 0.0f;
  for (int j = tid; j < NP2; j += 256) v += bsum2[j*NB + b];
  #pragma unroll
  for (int off=32; off>0; off>>=1) v += __shfl_down(v, off);
  if ((tid & 63) == 0) wred[tid >> 6] = v;

  int o = tid & 127, half = tid >> 7;
  float a = 0.0f;
  #pragma unroll 4
  for (int s = half; s < NP2; s += 2) a += pout2[(size_t)s*(NB*OUTS) + b*OUTS + o];
  accs[half*OUTS + o] = a;
  __syncthreads();
  if (tid < OUTS){
    float norm = wred[0] + wred[1] + wred[2] + wred[3];
    out[b*OUTS + tid] = (accs[tid] + accs[OUTS + tid]) / norm + bias[tid];
  }
}

// ---------------- launch ----------------
extern "C" void kernel_launch(void* const* d_in, const int* in_sizes, int n_in,
                              void* d_out, int out_size, void* d_ws, size_t ws_size,
                              hipStream_t stream) {
  const float* x    = (const float*)d_in[0];
  const float* th1  = (const float*)d_in[1];
  const float* th2  = (const float*)d_in[2];
  const float* mr   = (const float*)d_in[3];
  const float* mi   = (const float*)d_in[4];
  const float* wgt  = (const float*)d_in[5];
  const float* bias = (const float*)d_in[6];
  const int*   rows = (const int*)d_in[7];
  float* out = (float*)d_out;
  char* ws = (char*)d_ws;

  k_p1<<<NGRID, 256, 0, stream>>>(x, th1, th2, mr, mi, rows, ws);
  k_p2<<<NP2, 256, 0, stream>>>(wgt, ws);
  k_p3<<<NB, 256, 0, stream>>>(bias, ws, out);
}